// Round 1
// baseline (378.648 us; speedup 1.0000x reference)
//
#include <hip/hip_runtime.h>
#include <math.h>

#define NN 16384
#define EE 262144

typedef __bf16 v8bf __attribute__((ext_vector_type(8)));
typedef __bf16 v4bf __attribute__((ext_vector_type(4)));
typedef float  v4f  __attribute__((ext_vector_type(4)));
typedef float  v2f  __attribute__((ext_vector_type(2)));

// ---- workspace layout (units of 4-byte elements) ----
#define OFF_CNT     0                         // 2*NN ints
#define OFF_FILL    (2*NN)                    // 2*NN ints
#define OFF_ROWPTR  (4*NN)                    // 2*(NN+1) ints
#define OFF_COLSRC  98816                     // 2*EE ints (byte offsets)
#define OFF_H       623104                    // 2*NN*64 f32
#define OFF_HN      (OFF_H  + 2*NN*64)        // 2*NN*64 f32
#define OFF_Q       (OFF_HN + 2*NN*64)        // 2*NN*256 bf16 (512B rows)
#define OFF_KV      (OFF_Q  + 2*NN*128)       // 2*NN rows of 512 B: 32 groups of [K8|V8] fp8
#define OFF_R       (OFF_KV + 2*NN*128)       // 2*NN*64 f32

__device__ __forceinline__ float blo(unsigned u) { return __uint_as_float(u << 16); }
__device__ __forceinline__ float bhi(unsigned u) { return __uint_as_float(u & 0xffff0000u); }
__device__ __forceinline__ unsigned short f2b(float f) {
  __bf16 h = (__bf16)f;
  return *(unsigned short*)&h;
}

// ======================= CSR build =======================
__global__ void count_kernel(const int* __restrict__ ei, int* __restrict__ cnt) {
  int idx = blockIdx.x * 256 + threadIdx.x;
  if (idx >= 2 * EE) return;
  int et = idx >> 18;
  int j  = idx & (EE - 1);
  int dst = ei[et * 2 * EE + EE + j];
  atomicAdd(&cnt[et * NN + dst], 1);
}

__global__ __launch_bounds__(1024) void scan_kernel(const int* __restrict__ cnt,
                                                    int* __restrict__ rowptr,
                                                    int* __restrict__ fill) {
  int et = blockIdx.x;
  const int* c = cnt + et * NN;
  __shared__ int sums[1024];
  int tid = threadIdx.x;
  int base = tid * 16;
  int loc[16];
  int s = 0;
#pragma unroll
  for (int i = 0; i < 16; ++i) { loc[i] = s; s += c[base + i]; }
  sums[tid] = s;
  __syncthreads();
  for (int off = 1; off < 1024; off <<= 1) {
    int v = 0;
    if (tid >= off) v = sums[tid - off];
    __syncthreads();
    if (tid >= off) sums[tid] += v;
    __syncthreads();
  }
  int ebase = (tid == 0) ? 0 : sums[tid - 1];
  int* rp = rowptr + et * (NN + 1);
  int* fl = fill + et * NN;
#pragma unroll
  for (int i = 0; i < 16; ++i) {
    rp[base + i] = ebase + loc[i];
    fl[base + i] = ebase + loc[i];
  }
  if (tid == 1023) rp[NN] = sums[1023];
}

// colsrc holds BYTE offset of the src node's KV row: (et*NN + src) * 512
__global__ void scatter_kernel(const int* __restrict__ ei, int* __restrict__ fill,
                               int* __restrict__ colsrc) {
  int idx = blockIdx.x * 256 + threadIdx.x;
  if (idx >= 2 * EE) return;
  int et = idx >> 18;
  int j  = idx & (EE - 1);
  int src = ei[et * 2 * EE + j];
  int dst = ei[et * 2 * EE + EE + j];
  int pos = atomicAdd(&fill[et * NN + dst], 1);
  colsrc[et * EE + pos] = (et * NN + src) << 9;
}

// ======================= bf16 MFMA tiled GEMM (A staged once) =======================
// K=64 fixed. otype: 0=f32, 1=bf16, 2=fp8 K-interleaved, 3=fp8 V-interleaved.
// For otype 2/3 the KV row layout is 32 groups x [K0..K7 | V0..V7] (16 B / group).
struct GemmDesc {
  const float *A, *B, *bias, *bias2, *add;
  char* C;
  int Ncols, Cld, ntiles, gelu, otype;
};
struct GemmPack { GemmDesc d[8]; int nd; };

#define LDA 72   // padded bf16 row stride

__global__ __launch_bounds__(256) void gemm_mfma(GemmPack p) {
  GemmDesc g = p.d[blockIdx.y];
  const int row0 = blockIdx.x * 128;
  const int tid = threadIdx.x;
  const int w = tid >> 6, lane = tid & 63;
  const int l16 = lane & 15, quad = lane >> 4;

  __shared__ __bf16 As[128 * LDA];
  __shared__ __bf16 Bs[64 * LDA];

  // stage A rows once (K=64)
#pragma unroll
  for (int it = 0; it < 8; ++it) {
    int fi = it * 256 + tid;
    int grow = fi >> 4;
    int kq = (fi & 15) << 2;
    float4 a = *(const float4*)(g.A + (size_t)(row0 + grow) * 64 + kq);
    v4bf c = { (__bf16)a.x, (__bf16)a.y, (__bf16)a.z, (__bf16)a.w };
    *(v4bf*)&As[grow * LDA + kq] = c;
  }

  for (int ct0 = 0; ct0 < g.ntiles; ++ct0) {
    const int col0 = ct0 * 64;
    __syncthreads();   // A ready (iter 0) / prior MFMA done reading Bs
#pragma unroll
    for (int it = 0; it < 4; ++it) {
      int fi = it * 256 + tid;
      int kk = fi >> 4;
      int nq = (fi & 15) << 2;
      float4 b = *(const float4*)(g.B + (size_t)kk * g.Ncols + col0 + nq);
      Bs[(nq + 0) * LDA + kk] = (__bf16)b.x;
      Bs[(nq + 1) * LDA + kk] = (__bf16)b.y;
      Bs[(nq + 2) * LDA + kk] = (__bf16)b.z;
      Bs[(nq + 3) * LDA + kk] = (__bf16)b.w;
    }
    __syncthreads();

    v4f acc[2][4];
#pragma unroll
    for (int rt = 0; rt < 2; ++rt)
#pragma unroll
      for (int ct = 0; ct < 4; ++ct)
#pragma unroll
        for (int r = 0; r < 4; ++r) acc[rt][ct][r] = 0.f;

#pragma unroll
    for (int ks = 0; ks < 2; ++ks) {
      v8bf a0 = *(v8bf*)&As[(w * 32 + l16) * LDA + ks * 32 + quad * 8];
      v8bf a1 = *(v8bf*)&As[(w * 32 + 16 + l16) * LDA + ks * 32 + quad * 8];
#pragma unroll
      for (int ct = 0; ct < 4; ++ct) {
        v8bf bb = *(v8bf*)&Bs[(ct * 16 + l16) * LDA + ks * 32 + quad * 8];
        acc[0][ct] = __builtin_amdgcn_mfma_f32_16x16x32_bf16(a0, bb, acc[0][ct], 0, 0, 0);
        acc[1][ct] = __builtin_amdgcn_mfma_f32_16x16x32_bf16(a1, bb, acc[1][ct], 0, 0, 0);
      }
    }

    float bias_c[4];
#pragma unroll
    for (int ct = 0; ct < 4; ++ct) {
      int col = col0 + ct * 16 + l16;
      float b = g.bias ? g.bias[col] : 0.f;
      if (g.bias2) b += g.bias2[col];
      bias_c[ct] = b;
    }
#pragma unroll
    for (int rt = 0; rt < 2; ++rt)
#pragma unroll
      for (int r = 0; r < 4; ++r) {
        size_t row = row0 + w * 32 + rt * 16 + quad * 4 + r;
        char* cp = g.C + row * (size_t)g.Cld;
#pragma unroll
        for (int ct = 0; ct < 4; ++ct) {
          int col = col0 + ct * 16 + l16;
          float v = acc[rt][ct][r] + bias_c[ct];
          if (g.add) v += g.add[row * g.Ncols + col];
          if (g.gelu) v = 0.5f * v * (1.f + erff(v * 0.70710678118654752f));
          if (g.otype == 0)      *(float*)(cp + col * 4) = v;
          else if (g.otype == 1) *(unsigned short*)(cp + col * 2) = f2b(v);
          else {
            unsigned pk = __builtin_amdgcn_cvt_pk_fp8_f32(v, v, 0, false);
            int boff = ((col >> 3) << 4) + (col & 7) + ((g.otype == 3) ? 8 : 0);
            *(unsigned char*)(cp + boff) = (unsigned char)(pk & 0xff);
          }
        }
      }
  }
}

// ======================= fused FF (64 rows/block) + optional fused out-proj =======================
struct FFPack {
  const float *HN, *W1, *b1, *W2, *b2;
  float* H;
  const float *Wout, *bout;   // per-type [64][64], [64]
  float* outbuf;              // if non-null: write out = H@Wout+bout, skip H store
};

__global__ __launch_bounds__(256) void ff_fused(FFPack p) {
  const int t = blockIdx.y;
  const int row0 = blockIdx.x * 64;
  const int tid = threadIdx.x;
  const int w = tid >> 6, lane = tid & 63;
  const int l16 = lane & 15, quad = lane >> 4;

  const float* A  = p.HN + ((size_t)t * NN) * 64;
  const float* W1 = p.W1 + (size_t)t * 64 * 256;
  const float* b1 = p.b1 + t * 256;
  const float* W2 = p.W2 + (size_t)t * 256 * 64;
  const float* b2 = p.b2 + t * 64;

  __shared__ __bf16 As[64 * LDA];
  __shared__ __bf16 A2[64 * LDA];
  __shared__ __bf16 B1s[64 * LDA];
  __shared__ __bf16 B2s[64 * LDA];

#pragma unroll
  for (int it = 0; it < 4; ++it) {
    int fi = it * 256 + tid;
    int grow = fi >> 4;
    int kq = (fi & 15) << 2;
    float4 a = *(const float4*)(A + (size_t)(row0 + grow) * 64 + kq);
    v4bf c = { (__bf16)a.x, (__bf16)a.y, (__bf16)a.z, (__bf16)a.w };
    *(v4bf*)&As[grow * LDA + kq] = c;
  }

  v4f acc2[4];
#pragma unroll
  for (int ct = 0; ct < 4; ++ct)
#pragma unroll
    for (int r = 0; r < 4; ++r) acc2[ct][r] = 0.f;

  for (int c1 = 0; c1 < 4; ++c1) {
#pragma unroll
    for (int it = 0; it < 4; ++it) {
      int fi = it * 256 + tid;
      int kk = fi >> 4;
      int nq = (fi & 15) << 2;
      float4 b = *(const float4*)(W1 + (size_t)kk * 256 + c1 * 64 + nq);
      B1s[(nq + 0) * LDA + kk] = (__bf16)b.x;
      B1s[(nq + 1) * LDA + kk] = (__bf16)b.y;
      B1s[(nq + 2) * LDA + kk] = (__bf16)b.z;
      B1s[(nq + 3) * LDA + kk] = (__bf16)b.w;
      float4 b2v = *(const float4*)(W2 + (size_t)(c1 * 64 + kk) * 64 + nq);
      B2s[(nq + 0) * LDA + kk] = (__bf16)b2v.x;
      B2s[(nq + 1) * LDA + kk] = (__bf16)b2v.y;
      B2s[(nq + 2) * LDA + kk] = (__bf16)b2v.z;
      B2s[(nq + 3) * LDA + kk] = (__bf16)b2v.w;
    }
    __syncthreads();

    v4f acc1[4];
#pragma unroll
    for (int ct = 0; ct < 4; ++ct)
#pragma unroll
      for (int r = 0; r < 4; ++r) acc1[ct][r] = 0.f;
#pragma unroll
    for (int ks = 0; ks < 2; ++ks) {
      v8bf a = *(v8bf*)&As[(w * 16 + l16) * LDA + ks * 32 + quad * 8];
#pragma unroll
      for (int ct = 0; ct < 4; ++ct) {
        v8bf bb = *(v8bf*)&B1s[(ct * 16 + l16) * LDA + ks * 32 + quad * 8];
        acc1[ct] = __builtin_amdgcn_mfma_f32_16x16x32_bf16(a, bb, acc1[ct], 0, 0, 0);
      }
    }
#pragma unroll
    for (int ct = 0; ct < 4; ++ct) {
      float bb = b1[c1 * 64 + ct * 16 + l16];
#pragma unroll
      for (int r = 0; r < 4; ++r) {
        float v = acc1[ct][r] + bb;
        v = 0.5f * v * (1.f + erff(v * 0.70710678118654752f));
        A2[(w * 16 + quad * 4 + r) * LDA + ct * 16 + l16] = (__bf16)v;
      }
    }
#pragma unroll
    for (int ks = 0; ks < 2; ++ks) {
      v8bf a = *(v8bf*)&A2[(w * 16 + l16) * LDA + ks * 32 + quad * 8];
#pragma unroll
      for (int ct = 0; ct < 4; ++ct) {
        v8bf bb = *(v8bf*)&B2s[(ct * 16 + l16) * LDA + ks * 32 + quad * 8];
        acc2[ct] = __builtin_amdgcn_mfma_f32_16x16x32_bf16(a, bb, acc2[ct], 0, 0, 0);
      }
    }
    __syncthreads();
  }

  if (!p.outbuf) {
    // standard epilogue: H = hr + acc2 + b2
#pragma unroll
    for (int ct = 0; ct < 4; ++ct) {
      int col = ct * 16 + l16;
      float bb = b2[col];
#pragma unroll
      for (int r = 0; r < 4; ++r) {
        size_t row = (size_t)t * NN + row0 + w * 16 + quad * 4 + r;
        float v = acc2[ct][r] + bb + p.HN[row * 64 + col];
        p.H[row * 64 + col] = v;
      }
    }
    return;
  }

  // ---- fused output projection (last layer): out = (hr+ff) @ Wout + bout ----
#pragma unroll
  for (int ct = 0; ct < 4; ++ct) {
    int col = ct * 16 + l16;
    float bb = b2[col];
#pragma unroll
    for (int r = 0; r < 4; ++r) {
      int lrow = w * 16 + quad * 4 + r;
      size_t row = (size_t)t * NN + row0 + lrow;
      float v = acc2[ct][r] + bb + p.HN[row * 64 + col];
      A2[lrow * LDA + col] = (__bf16)v;
    }
  }
  {
    const float* Wo = p.Wout + (size_t)t * 64 * 64;
#pragma unroll
    for (int it = 0; it < 4; ++it) {
      int fi = it * 256 + tid;
      int kk = fi >> 4;
      int nq = (fi & 15) << 2;
      float4 b = *(const float4*)(Wo + (size_t)kk * 64 + nq);
      B1s[(nq + 0) * LDA + kk] = (__bf16)b.x;
      B1s[(nq + 1) * LDA + kk] = (__bf16)b.y;
      B1s[(nq + 2) * LDA + kk] = (__bf16)b.z;
      B1s[(nq + 3) * LDA + kk] = (__bf16)b.w;
    }
  }
  __syncthreads();

  v4f acc3[4];
#pragma unroll
  for (int ct = 0; ct < 4; ++ct)
#pragma unroll
    for (int r = 0; r < 4; ++r) acc3[ct][r] = 0.f;
#pragma unroll
  for (int ks = 0; ks < 2; ++ks) {
    v8bf a = *(v8bf*)&A2[(w * 16 + l16) * LDA + ks * 32 + quad * 8];
#pragma unroll
    for (int ct = 0; ct < 4; ++ct) {
      v8bf bb = *(v8bf*)&B1s[(ct * 16 + l16) * LDA + ks * 32 + quad * 8];
      acc3[ct] = __builtin_amdgcn_mfma_f32_16x16x32_bf16(a, bb, acc3[ct], 0, 0, 0);
    }
  }
  const float* bo = p.bout + t * 64;
#pragma unroll
  for (int ct = 0; ct < 4; ++ct) {
    int col = ct * 16 + l16;
    float bb = bo[col];
#pragma unroll
    for (int r = 0; r < 4; ++r) {
      size_t row = (size_t)t * NN + row0 + w * 16 + quad * 4 + r;
      p.outbuf[row * 64 + col] = acc3[ct][r] + bb;
    }
  }
}

// ======================= edge aggregation + beta + LN =======================
// grid.y = edge type; one wave / dst node.
// Lane layout: half = lane>>5 (which edge of a pair), lh = lane&31 = head*8 + c8.
// Each lane owns 8 channels (head*64 + c8*8 .. +7); one dwordx4 fetches K8|V8 fp8.
// 2 streams x 2 halves = 4 independent gather chains; colsrc prefetched 1 iter ahead.
struct AggPack {
  const unsigned short *Q;   // [2*NN][256] bf16 (dst-type indexed)
  const char *KV;            // [2*NN] rows of 512 B: 32 x [K8|V8] (src-type indexed)
  const float *R;            // [2*NN][64]
  const float *Wb;
  const float *Hin;
  const float *lng, *lnb;
  float* outHR;
  const int *rowptr;
  const int *colsrc;         // byte offsets
};

__global__ __launch_bounds__(256) void agg_kernel(AggPack p) {
  const int et = blockIdx.y, d = 1 - et;
  int wid = __builtin_amdgcn_readfirstlane(threadIdx.x >> 6);
  int lane = threadIdx.x & 63;
  int node = blockIdx.x * 4 + wid;
  int lh = lane & 31;          // head*8 + c8
  int half = lane >> 5;

  const int* rp = p.rowptr + et * (NN + 1);
  const int* cs = p.colsrc + et * EE;
  int start = rp[node], end = rp[node + 1];
  int len = end - start;
  int gnode = d * NN + node;

  // Q fragment: 8 channels (16 B) at byte offset lh*16 of the 512B row
  uint4 qw = *(const uint4*)(p.Q + ((size_t)gnode << 8) + lh * 8);
  float q0 = blo(qw.x) * 0.125f, q1 = bhi(qw.x) * 0.125f;
  float q2 = blo(qw.y) * 0.125f, q3 = bhi(qw.y) * 0.125f;
  float q4 = blo(qw.z) * 0.125f, q5 = bhi(qw.z) * 0.125f;
  float q6 = blo(qw.w) * 0.125f, q7 = bhi(qw.w) * 0.125f;

  int mid = start + (len >> 1);
  int last = end - 1;
  float dsum0 = 0.f, dsum1 = 0.f;
  float acc0[8], acc1[8];
#pragma unroll
  for (int i = 0; i < 8; ++i) { acc0[i] = 0.f; acc1[i] = 0.f; }

  int maxn = (len + 3) >> 2;       // pairs per stream (2 streams, 2 edges/iter each)
  int j0 = start + half, j1 = mid + half;
  bool a0 = j0 < mid, a1 = j1 < end;
  int o0 = 0, o1 = 0;
  if (len > 0) {                   // wave-uniform branch
    o0 = cs[a0 ? j0 : last];
    o1 = cs[a1 ? j1 : last];
  }
  int lb = lh * 16;
  for (int it = 0; it < maxn; ++it) {
    uint4 kv0 = *(const uint4*)(p.KV + (size_t)(o0 + lb));
    uint4 kv1 = *(const uint4*)(p.KV + (size_t)(o1 + lb));
    float w0 = a0 ? 1.f : 0.f;
    float w1 = a1 ? 1.f : 0.f;
    // prefetch next pair's offsets (hides cs->KV chain under compute)
    j0 += 2; j1 += 2;
    a0 = j0 < mid; a1 = j1 < end;
    o0 = cs[a0 ? j0 : last];
    o1 = cs[a1 ? j1 : last];

    // ---- stream 0 ----
    {
      v2f ka = __builtin_amdgcn_cvt_pk_f32_fp8((int)kv0.x, false);
      v2f kb = __builtin_amdgcn_cvt_pk_f32_fp8((int)kv0.x, true);
      v2f kc = __builtin_amdgcn_cvt_pk_f32_fp8((int)kv0.y, false);
      v2f kd = __builtin_amdgcn_cvt_pk_f32_fp8((int)kv0.y, true);
      float pd = q0 * ka[0] + q1 * ka[1] + q2 * kb[0] + q3 * kb[1]
               + q4 * kc[0] + q5 * kc[1] + q6 * kd[0] + q7 * kd[1];
      pd += __shfl_xor(pd, 1);
      pd += __shfl_xor(pd, 2);
      pd += __shfl_xor(pd, 4);
      float wgt = w0 * __expf(pd);
      v2f va = __builtin_amdgcn_cvt_pk_f32_fp8((int)kv0.z, false);
      v2f vb = __builtin_amdgcn_cvt_pk_f32_fp8((int)kv0.z, true);
      v2f vc = __builtin_amdgcn_cvt_pk_f32_fp8((int)kv0.w, false);
      v2f vd = __builtin_amdgcn_cvt_pk_f32_fp8((int)kv0.w, true);
      dsum0 += wgt;
      acc0[0] += wgt * va[0]; acc0[1] += wgt * va[1];
      acc0[2] += wgt * vb[0]; acc0[3] += wgt * vb[1];
      acc0[4] += wgt * vc[0]; acc0[5] += wgt * vc[1];
      acc0[6] += wgt * vd[0]; acc0[7] += wgt * vd[1];
    }
    // ---- stream 1 ----
    {
      v2f ka = __builtin_amdgcn_cvt_pk_f32_fp8((int)kv1.x, false);
      v2f kb = __builtin_amdgcn_cvt_pk_f32_fp8((int)kv1.x, true);
      v2f kc = __builtin_amdgcn_cvt_pk_f32_fp8((int)kv1.y, false);
      v2f kd = __builtin_amdgcn_cvt_pk_f32_fp8((int)kv1.y, true);
      float pd = q0 * ka[0] + q1 * ka[1] + q2 * kb[0] + q3 * kb[1]
               + q4 * kc[0] + q5 * kc[1] + q6 * kd[0] + q7 * kd[1];
      pd += __shfl_xor(pd, 1);
      pd += __shfl_xor(pd, 2);
      pd += __shfl_xor(pd, 4);
      float wgt = w1 * __expf(pd);
      v2f va = __builtin_amdgcn_cvt_pk_f32_fp8((int)kv1.z, false);
      v2f vb = __builtin_amdgcn_cvt_pk_f32_fp8((int)kv1.z, true);
      v2f vc = __builtin_amdgcn_cvt_pk_f32_fp8((int)kv1.w, false);
      v2f vd = __builtin_amdgcn_cvt_pk_f32_fp8((int)kv1.w, true);
      dsum1 += wgt;
      acc1[0] += wgt * va[0]; acc1[1] += wgt * va[1];
      acc1[2] += wgt * vb[0]; acc1[3] += wgt * vb[1];
      acc1[4] += wgt * vc[0]; acc1[5] += wgt * vc[1];
      acc1[6] += wgt * vd[0]; acc1[7] += wgt * vd[1];
    }
  }

  // per-head denominator: merge streams + the two edge-halves
  float dn = dsum0 + dsum1;
  dn += __shfl_xor(dn, 32);
  float inv = (len > 0) ? (0.25f / dn) : 0.f;

  // merge halves, normalize per head, then mean over heads (xor 8,16)
  float o_[8];
#pragma unroll
  for (int i = 0; i < 8; ++i) {
    float a = acc0[i] + acc1[i];
    a += __shfl_xor(a, 32);
    a *= inv;
    a += __shfl_xor(a, 8);
    a += __shfl_xor(a, 16);
    o_[i] = a;
  }

  // epilogue: channels cc..cc+7 where cc = (lane&7)*8 (replicated 8x across wave)
  int cc = (lane & 7) << 3;
  const float* rptr = p.R + (size_t)gnode * 64 + cc;
  float4 r0 = *(const float4*)(rptr);
  float4 r1 = *(const float4*)(rptr + 4);
  float rr[8] = { r0.x, r0.y, r0.z, r0.w, r1.x, r1.y, r1.z, r1.w };

  const float* wb = p.Wb + et * 192;
  float4 wo0 = *(const float4*)(wb + cc),       wo1 = *(const float4*)(wb + cc + 4);
  float4 wr0 = *(const float4*)(wb + 64 + cc),  wr1 = *(const float4*)(wb + 64 + cc + 4);
  float4 wd0 = *(const float4*)(wb + 128 + cc), wd1 = *(const float4*)(wb + 128 + cc + 4);
  float wov[8] = { wo0.x, wo0.y, wo0.z, wo0.w, wo1.x, wo1.y, wo1.z, wo1.w };
  float wrv[8] = { wr0.x, wr0.y, wr0.z, wr0.w, wr1.x, wr1.y, wr1.z, wr1.w };
  float wdv[8] = { wd0.x, wd0.y, wd0.z, wd0.w, wd1.x, wd1.y, wd1.z, wd1.w };
  float part = 0.f;
#pragma unroll
  for (int i = 0; i < 8; ++i)
    part += o_[i] * wov[i] + rr[i] * wrv[i] + (o_[i] - rr[i]) * wdv[i];
  part += __shfl_xor(part, 1);
  part += __shfl_xor(part, 2);
  part += __shfl_xor(part, 4);
  float beta = 1.f / (1.f + __expf(-part));

  const float* hptr = p.Hin + (size_t)gnode * 64 + cc;
  float4 h0 = *(const float4*)(hptr);
  float4 h1 = *(const float4*)(hptr + 4);
  float hh[8] = { h0.x, h0.y, h0.z, h0.w, h1.x, h1.y, h1.z, h1.w };
  float y[8];
  float sa = 0.f, sb = 0.f;
#pragma unroll
  for (int i = 0; i < 8; ++i) {
    float v = hh[i] + beta * rr[i] + (1.f - beta) * o_[i];
    y[i] = v;
    sa += v;
    sb += v * v;
  }
  sa += __shfl_xor(sa, 1); sb += __shfl_xor(sb, 1);
  sa += __shfl_xor(sa, 2); sb += __shfl_xor(sb, 2);
  sa += __shfl_xor(sa, 4); sb += __shfl_xor(sb, 4);
  float mu = sa * (1.f / 64.f);
  float var = sb * (1.f / 64.f) - mu * mu;
  float rs = rsqrtf(var + 1e-5f);

  if (lane < 8) {
    const float* lng = p.lng + d * 64 + cc;
    const float* lnb = p.lnb + d * 64 + cc;
    float4 g0 = *(const float4*)(lng);
    float4 g1 = *(const float4*)(lng + 4);
    float4 bb0 = *(const float4*)(lnb);
    float4 bb1 = *(const float4*)(lnb + 4);
    float4 res0, res1;
    res0.x = (y[0] - mu) * rs * g0.x + bb0.x;
    res0.y = (y[1] - mu) * rs * g0.y + bb0.y;
    res0.z = (y[2] - mu) * rs * g0.z + bb0.z;
    res0.w = (y[3] - mu) * rs * g0.w + bb0.w;
    res1.x = (y[4] - mu) * rs * g1.x + bb1.x;
    res1.y = (y[5] - mu) * rs * g1.y + bb1.y;
    res1.z = (y[6] - mu) * rs * g1.z + bb1.z;
    res1.w = (y[7] - mu) * rs * g1.w + bb1.w;
    float* op = p.outHR + (size_t)gnode * 64 + cc;
    *(float4*)(op) = res0;
    *(float4*)(op + 4) = res1;
  }
}

// ======================= host =======================
static void add_desc(GemmPack& p, const float* A, const float* B,
                     const float* bias, const float* bias2, const float* add,
                     void* C, int Nc, int Cld, int gelu, int otype) {
  GemmDesc& g = p.d[p.nd++];
  g.A = A; g.B = B; g.bias = bias; g.bias2 = bias2; g.add = add; g.C = (char*)C;
  g.Ncols = Nc; g.Cld = Cld; g.ntiles = Nc / 64;
  g.gelu = gelu; g.otype = otype;
}

extern "C" void kernel_launch(void* const* d_in, const int* in_sizes, int n_in,
                              void* d_out, int out_size, void* d_ws, size_t ws_size,
                              hipStream_t stream) {
  const float* x        = (const float*)d_in[0];
  const int*   ei       = (const int*)d_in[1];
  const float* W_in     = (const float*)d_in[2];
  const float* b_in     = (const float*)d_in[3];
  const float* type_emb = (const float*)d_in[4];
  const float* pos      = (const float*)d_in[5];
  const float* Wq       = (const float*)d_in[6];
  const float* bq       = (const float*)d_in[7];
  const float* Wk       = (const float*)d_in[8];
  const float* bk       = (const float*)d_in[9];
  const float* Wv       = (const float*)d_in[10];
  const float* bv       = (const float*)d_in[11];
  const float* Wskip    = (const float*)d_in[12];
  const float* bskip    = (const float*)d_in[13];
  const float* Wbeta    = (const float*)d_in[14];
  const float* ln_g     = (const float*)d_in[15];
  const float* ln_b     = (const float*)d_in[16];
  const float* ff_W1    = (const float*)d_in[17];
  const float* ff_b1    = (const float*)d_in[18];
  const float* ff_W2    = (const float*)d_in[19];
  const float* ff_b2    = (const float*)d_in[20];
  const float* W_out    = (const float*)d_in[21];
  const float* b_out    = (const float*)d_in[22];
  float* out = (float*)d_out;

  int*   wsi = (int*)d_ws;
  float* wsf = (float*)d_ws;
  int* cnt    = wsi + OFF_CNT;
  int* fill   = wsi + OFF_FILL;
  int* rowptr = wsi + OFF_ROWPTR;
  int* colsrc = wsi + OFF_COLSRC;
  float* H  = wsf + OFF_H;
  float* HN = wsf + OFF_HN;
  unsigned short* Qb = (unsigned short*)(wsf + OFF_Q);
  char* KVb = (char*)(wsf + OFF_KV);
  float* Rb = wsf + OFF_R;

  // ---- CSR build ----
  hipMemsetAsync(cnt, 0, 2 * NN * sizeof(int), stream);
  count_kernel<<<dim3(2 * EE / 256), dim3(256), 0, stream>>>(ei, cnt);
  scan_kernel<<<dim3(2), dim3(1024), 0, stream>>>(cnt, rowptr, fill);
  scatter_kernel<<<dim3(2 * EE / 256), dim3(256), 0, stream>>>(ei, fill, colsrc);

  // ---- input projection ----
  {
    GemmPack p{};
    for (int t = 0; t < 2; ++t)
      add_desc(p, x + (size_t)t * NN * 64, W_in + t * 64 * 64,
               b_in + t * 64, type_emb + t * 64, pos + (size_t)t * NN * 64,
               H + (size_t)t * NN * 64, 64, 256, 0, 0);
    gemm_mfma<<<dim3(128, p.nd), dim3(256), 0, stream>>>(p);
  }

  for (int l = 0; l < 2; ++l) {
    // one batched GEMM for both edge types: q,k,v,skip x 2
    {
      GemmPack p{};
      for (int et = 0; et < 2; ++et) {
        int s = et, d = 1 - et;
        int we = l * 2 + et;
        const float* hs = H + (size_t)s * NN * 64;
        const float* hd = H + (size_t)d * NN * 64;
        add_desc(p, hd, Wq + (size_t)we * 64 * 256, bq + we * 256,
                 nullptr, nullptr, (char*)Qb + (size_t)d * NN * 512, 256, 512, 0, 1);
        add_desc(p, hs, Wk + (size_t)we * 64 * 256, bk + we * 256,
                 nullptr, nullptr, KVb + (size_t)s * NN * 512, 256, 512, 0, 2);
        add_desc(p, hs, Wv + (size_t)we * 64 * 256, bv + we * 256,
                 nullptr, nullptr, KVb + (size_t)s * NN * 512, 256, 512, 0, 3);
        add_desc(p, hd, Wskip + (size_t)we * 64 * 64, bskip + we * 64,
                 nullptr, nullptr, Rb + (size_t)d * NN * 64, 64, 256, 0, 0);
      }
      gemm_mfma<<<dim3(128, p.nd), dim3(256), 0, stream>>>(p);
    }

    AggPack ap;
    ap.Q = Qb; ap.KV = KVb; ap.R = Rb;
    ap.Wb = Wbeta + l * 2 * 192;
    ap.Hin = H;
    ap.lng = ln_g + l * 128;
    ap.lnb = ln_b + l * 128;
    ap.outHR = HN;
    ap.rowptr = rowptr;
    ap.colsrc = colsrc;
    agg_kernel<<<dim3(NN / 4, 2), dim3(256), 0, stream>>>(ap);

    FFPack fp;
    fp.HN = HN;
    fp.W1 = ff_W1 + (size_t)l * 2 * 64 * 256;
    fp.b1 = ff_b1 + l * 2 * 256;
    fp.W2 = ff_W2 + (size_t)l * 2 * 256 * 64;
    fp.b2 = ff_b2 + l * 2 * 64;
    fp.H  = H;
    fp.Wout = W_out;
    fp.bout = b_out;
    fp.outbuf = (l == 1) ? out : nullptr;   // fuse output projection into last FF
    ff_fused<<<dim3(NN / 64, 2), dim3(256), 0, stream>>>(fp);
  }
}